// Round 4
// baseline (282.390 us; speedup 1.0000x reference)
//
#include <hip/hip_runtime.h>
#include <hip/hip_bf16.h>

typedef __attribute__((ext_vector_type(8))) int   i32x8;   // 32 B = fp8 MFMA A/B operand (8 VGPRs)
typedef __attribute__((ext_vector_type(4))) int   i32x4;
typedef __attribute__((ext_vector_type(4))) float f32x4;   // MFMA C/D

constexpr int BB = 4096;   // batch B
constexpr int D  = 256;    // feature dim
constexpr int R2 = 8192;   // 2B rows of z
constexpr int NSPLIT = 32; // column splits (256 cols per tile)
constexpr int CPB = R2 / NSPLIT;        // 256 cols per tile = 64 KB LDS
constexpr int NG  = CPB / 16;           // 16 n-groups of 16 cols per wave
constexpr int NTRI = NSPLIT * (NSPLIT + 1) / 2;   // 528 upper-triangle tile pairs
// z pre-scaled by sqrt(2*log2(e)): dot = log2(e)*sim/TEMP -> exp2(dot) = exp(sim/TEMP).
constexpr float SCALE = 1.6986436005760381f;
constexpr float E2 = 7.38905609893065f;  // exp(2) == exp(diag sim)

// Async 16B/lane global->LDS DMA. LDS dest is wave-uniform base + lane*16 (HW);
// global source is per-lane.
__device__ __forceinline__ void async16(const unsigned char* g, unsigned char* l) {
    __builtin_amdgcn_global_load_lds(
        (const __attribute__((address_space(1))) void*)g,
        (__attribute__((address_space(3))) void*)l,
        16, 0, 0);
}

// Unit-scale (E8M0 127 = 2^0) MX-fp8 MFMA, fmt A/B = fp8-e4m3. Verified correct R5-R17.
#define MFMA8(A, B, C) \
    __builtin_amdgcn_mfma_scale_f32_16x16x128_f8f6f4((A), (B), (C), 0, 0, 0, 127, 0, 127)

// Kernel A: L2-normalize rows, scale by sqrt(2*log2e), store fp8-e4m3 z[8192][256];
// pos[k] = 2*cos(xi_k, xj_k) in fp32. One wave per pair k. Also zero-inits out[0].
__global__ __launch_bounds__(256) void norm_kernel(const float* __restrict__ xi,
                                                   const float* __restrict__ xj,
                                                   int* __restrict__ z8,
                                                   float* __restrict__ pos,
                                                   float* __restrict__ out) {
    const int wid = threadIdx.x >> 6, lane = threadIdx.x & 63;
    const int k = blockIdx.x * 4 + wid;
    if (blockIdx.x == 0 && threadIdx.x == 0) out[0] = 0.f;
    const float4* a4 = reinterpret_cast<const float4*>(xi + (size_t)k * D);
    const float4* b4 = reinterpret_cast<const float4*>(xj + (size_t)k * D);
    float4 a = a4[lane], b = b4[lane];
    float ssi = a.x*a.x + a.y*a.y + a.z*a.z + a.w*a.w;
    float ssj = b.x*b.x + b.y*b.y + b.z*b.z + b.w*b.w;
    float dot = a.x*b.x + a.y*b.y + a.z*b.z + a.w*b.w;
#pragma unroll
    for (int off = 32; off; off >>= 1) {
        ssi += __shfl_xor(ssi, off);
        ssj += __shfl_xor(ssj, off);
        dot += __shfl_xor(dot, off);
    }
    const float inv_i = 1.0f / fmaxf(sqrtf(ssi), 1e-12f);
    const float inv_j = 1.0f / fmaxf(sqrtf(ssj), 1e-12f);
    const float si = inv_i * SCALE, sj = inv_j * SCALE;
    int pi = __builtin_amdgcn_cvt_pk_fp8_f32(a.x*si, a.y*si, 0, false);
    pi     = __builtin_amdgcn_cvt_pk_fp8_f32(a.z*si, a.w*si, pi, true);
    int pj = __builtin_amdgcn_cvt_pk_fp8_f32(b.x*sj, b.y*sj, 0, false);
    pj     = __builtin_amdgcn_cvt_pk_fp8_f32(b.z*sj, b.w*sj, pj, true);
    z8[(size_t)k * 64 + lane]        = pi;
    z8[(size_t)(k + BB) * 64 + lane] = pj;
    if (lane == 0) pos[k] = dot * inv_i * inv_j * 2.0f;
}

// Kernel B (R22): triangle (R21-verified indexing) + REGISTER col-accumulation.
// R21 post-mortem: per-iteration LDS atomicAdd (64 lanes, 4-way same-address
// RMW) clogged the LDS pipe AND broke the compiler's software pipeline
// (VGPR 184->52, MfmaUtil 6.4%, sim 47.7us — slower than full grid at half
// the MFMA work). Fix: col-sums accumulate in cacc[NG] registers (FULL unroll
// -> static indices -> stays in VGPRs, rule #20); inner loop is again pure
// ds_read+MFMA+exp. End-game: per n, 2x shfl_xor over quad lanes, then ONE
// LDS atomic per (wave,n) — 16 atomics/wave total vs 16/wave/iteration.
//   row-side: partial[by][bx*256 + r]   (unique writer: this block)
//   col-side: partial[bx][by*256 + c]   (unique writer: mirror never launched)
// Coverage: row r tile t: s>=t from row-side of (t,s), s<t from col-side of
// (s,t) — each partial[s][r] written exactly once; reduce_kernel unchanged.
// fp8 layouts + swizzles + A-frag pin verified R5-R17; triangle verified R21.
__global__ __launch_bounds__(512, 4) void sim_kernel(const unsigned char* __restrict__ z8,
                                                     float* __restrict__ partial) {
    __shared__ unsigned char tb[CPB * D];   // 64 KB tile of B columns
    __shared__ float colacc[CPB];           // col-sums over this block's rows
    const int tid = threadIdx.x;
    const int wid = tid >> 6, lane = tid & 63;
    const int lrow = lane & 15, quad = lane >> 4;

    // Decode linear block id -> upper-triangle (bx, by), by >= bx.
    int t = blockIdx.x, bx = 0;
    while (t >= (NSPLIT - bx)) { t -= (NSPLIT - bx); ++bx; }
    const int by = bx + t;

    const int r0 = bx * 256 + wid * 32;     // this wave's 32 rows (row tile bx)
    const int cbase = by * CPB;             // this block's 256 cols (col tile by)

    if (tid < CPB) colacc[tid] = 0.f;       // ordered by the staging barrier

    // Staging: 8 rounds x 8 KB (512 thr x 16 B). Round i, thread tid writes
    // physical granule-linear i*512 + tid -> row r = i*32 + (tid>>4), physical
    // granule p = tid&15. Source logical granule = p ^ (r&15) = (tid&15)^((tid>>4)&15).
    {
        const int srcg = (tid & 15) ^ ((tid >> 4) & 15);
        const unsigned char* gs = z8 + (size_t)(cbase + (tid >> 4)) * D + srcg * 16;
        unsigned char* ds = tb + tid * 16;
#pragma unroll
        for (int i = 0; i < 8; ++i)
            async16(gs + (size_t)i * 32 * D, ds + i * 8192);
    }

    // A fragments: 32 rows x K=256. Layout (16x16x128 f8f6f4): row = lane&15,
    // k-bytes = (lane>>4)*32 + linear; k-half 1 at +128. Pinned vs remat (R9/R10).
    const unsigned char* abase = z8 + (size_t)(r0 + lrow) * D + quad * 32;
    i32x8 a0k0 = *reinterpret_cast<const i32x8*>(abase             );
    i32x8 a0k1 = *reinterpret_cast<const i32x8*>(abase        + 128);
    i32x8 a1k0 = *reinterpret_cast<const i32x8*>(abase + 16*D      );
    i32x8 a1k1 = *reinterpret_cast<const i32x8*>(abase + 16*D + 128);
    asm volatile("" : "+v"(a0k0), "+v"(a0k1), "+v"(a1k0), "+v"(a1k1));

    f32x4 racc0 = {0.f,0.f,0.f,0.f}, racc1 = {0.f,0.f,0.f,0.f};
    float cacc[NG];   // per-lane col-sum for col n*16+lrow (8 rows each) — VGPRs

    __syncthreads();   // staging DMA drained, tile + colacc init complete

    // Pure-LDS loop: per group, 4 ds_read_b128 + 4 MFMA + 8 exp2 + 8 VALU adds.
    // Read swizzle (verified): col row = n*16+lrow, physical granule = logical ^ lrow;
    // b128 pairs (pe, pe^1) reassemble the 32-B operand halves.
    // FULL unroll (NG=16): cacc[n] indices static -> registers, and the
    // scheduler can re-pipeline B-reads under the 128-VGPR cap.
    const int pe0 = (quad * 2) ^ lrow;        // k-half 0 even granule
    const int pe1 = (8 + quad * 2) ^ lrow;    // k-half 1 even granule
    const unsigned char* rbp = tb + lrow * D;
#pragma unroll
    for (int n = 0; n < NG; ++n) {
        const i32x4 lo0 = *reinterpret_cast<const i32x4*>(rbp + pe0*16);
        const i32x4 hi0 = *reinterpret_cast<const i32x4*>(rbp + (pe0^1)*16);
        const i32x4 lo1 = *reinterpret_cast<const i32x4*>(rbp + pe1*16);
        const i32x4 hi1 = *reinterpret_cast<const i32x4*>(rbp + (pe1^1)*16);
        rbp += 16 * D;
        const i32x8 b0 = __builtin_shufflevector(lo0, hi0, 0,1,2,3,4,5,6,7);
        const i32x8 b1 = __builtin_shufflevector(lo1, hi1, 0,1,2,3,4,5,6,7);

        f32x4 c0 = {0.f,0.f,0.f,0.f}, c1 = {0.f,0.f,0.f,0.f};
        c0 = MFMA8(a0k0, b0, c0);  c0 = MFMA8(a0k1, b1, c0);
        c1 = MFMA8(a1k0, b0, c1);  c1 = MFMA8(a1k1, b1, c1);

        const float e0 = __builtin_amdgcn_exp2f(c0[0]);
        const float e1 = __builtin_amdgcn_exp2f(c0[1]);
        const float e2 = __builtin_amdgcn_exp2f(c0[2]);
        const float e3 = __builtin_amdgcn_exp2f(c0[3]);
        const float e4 = __builtin_amdgcn_exp2f(c1[0]);
        const float e5 = __builtin_amdgcn_exp2f(c1[1]);
        const float e6 = __builtin_amdgcn_exp2f(c1[2]);
        const float e7 = __builtin_amdgcn_exp2f(c1[3]);
        racc0[0] += e0;  racc0[1] += e1;  racc0[2] += e2;  racc0[3] += e3;
        racc1[0] += e4;  racc1[1] += e5;  racc1[2] += e6;  racc1[3] += e7;
        // Col contribution of this lane's 8 rows to col n*16+lrow (register only).
        cacc[n] = ((e0 + e1) + (e2 + e3)) + ((e4 + e5) + (e6 + e7));
    }

    // Row sums: reduce over lane bits 0-3 (the col index); row = quad*4 + j.
#define REDUCE_STORE(RV, M)                                                     \
    {                                                                           \
        _Pragma("unroll")                                                       \
        for (int j = 0; j < 4; ++j) {                                           \
            float v = (RV)[j];                                                  \
            v += __shfl_xor(v, 1);                                              \
            v += __shfl_xor(v, 2);                                              \
            v += __shfl_xor(v, 4);                                              \
            v += __shfl_xor(v, 8);                                              \
            if (lrow == 0)                                                      \
                partial[(size_t)by * R2 + r0 + (M)*16 + quad*4 + j] = v;        \
        }                                                                       \
    }
    REDUCE_STORE(racc0, 0)
    REDUCE_STORE(racc1, 1)
#undef REDUCE_STORE

    // Col-side end-game (off-diagonal only): reduce cacc over the 4 quad lanes
    // (shfl over lane bits 4,5), then ONE LDS atomic per (wave, n) — 16 lanes,
    // 16 distinct banks, 8-way cross-wave contention total per address.
    if (bx != by) {
#pragma unroll
        for (int n = 0; n < NG; ++n) {
            float v = cacc[n];
            v += __shfl_xor(v, 16);
            v += __shfl_xor(v, 32);
            if (quad == 0) atomicAdd(&colacc[n * 16 + lrow], v);
        }
    }
    __syncthreads();   // all waves' colacc atomics drained
    if (bx != by && tid < CPB)
        partial[(size_t)bx * R2 + cbase + tid] = colacc[tid];
}

// Kernel C: loss_r = log(exp(p_r) + S_r - e^2) - p_r ; atomicAdd(out, blocksum/R2).
// 32 blocks x 256 threads (256 rows each); out zero-initialized by norm_kernel.
__global__ __launch_bounds__(256) void reduce_kernel(const float* __restrict__ partial,
                                                     const float* __restrict__ pos,
                                                     float* __restrict__ out) {
    __shared__ float wsum[4];
    const int tid = threadIdx.x;
    const int r = blockIdx.x * 256 + tid;
    float S = 0.f;
#pragma unroll
    for (int s = 0; s < NSPLIT; ++s) S += partial[(size_t)s * R2 + r];
    const float p = pos[r & (BB - 1)];
    float lsum = __logf(__expf(p) + S - E2) - p;
#pragma unroll
    for (int off = 32; off; off >>= 1) lsum += __shfl_xor(lsum, off);
    if ((tid & 63) == 0) wsum[tid >> 6] = lsum;
    __syncthreads();
    if (tid == 0) {
        float t = wsum[0] + wsum[1] + wsum[2] + wsum[3];
        atomicAdd(out, t * (1.0f / (float)R2));
    }
}

extern "C" void kernel_launch(void* const* d_in, const int* in_sizes, int n_in,
                              void* d_out, int out_size, void* d_ws, size_t ws_size,
                              hipStream_t stream) {
    (void)in_sizes; (void)n_in; (void)out_size; (void)ws_size;
    const float* xi = (const float*)d_in[0];
    const float* xj = (const float*)d_in[1];
    float* out = (float*)d_out;

    unsigned char* z8 = (unsigned char*)d_ws;                                  // 8192*256 = 2 MB
    float* partial = (float*)((char*)d_ws + (size_t)R2 * D);                   // 32*8192*4 = 1 MB
    float* pos     = (float*)((char*)d_ws + (size_t)R2 * D + (size_t)NSPLIT*R2*4);  // 16 KB

    norm_kernel<<<BB / 4, 256, 0, stream>>>(xi, xj, (int*)z8, pos, out);
    sim_kernel<<<NTRI, 512, 0, stream>>>(z8, partial);
    reduce_kernel<<<R2 / 256, 256, 0, stream>>>(partial, pos, out);
}

// Round 5
// 84.891 us; speedup vs baseline: 3.3265x; 3.3265x over previous
//
#include <hip/hip_runtime.h>
#include <hip/hip_bf16.h>

typedef __attribute__((ext_vector_type(8))) int   i32x8;   // 32 B = fp8 MFMA A/B operand (8 VGPRs)
typedef __attribute__((ext_vector_type(4))) int   i32x4;
typedef __attribute__((ext_vector_type(4))) float f32x4;   // MFMA C/D

constexpr int BB = 4096;   // batch B
constexpr int D  = 256;    // feature dim
constexpr int R2 = 8192;   // 2B rows of z
constexpr int NSPLIT = 32; // column splits (256 cols per tile)
constexpr int CPB = R2 / NSPLIT;        // 256 cols per tile = 64 KB LDS
constexpr int NG  = CPB / 16;           // 16 n-groups of 16 cols per wave
constexpr int NTRI = NSPLIT * (NSPLIT + 1) / 2;   // 528 upper-triangle tile pairs
// z pre-scaled by sqrt(2*log2(e)): dot = log2(e)*sim/TEMP -> exp2(dot) = exp(sim/TEMP).
constexpr float SCALE = 1.6986436005760381f;
constexpr float E2 = 7.38905609893065f;  // exp(2) == exp(diag sim)

// Async 16B/lane global->LDS DMA. LDS dest is wave-uniform base + lane*16 (HW);
// global source is per-lane.
__device__ __forceinline__ void async16(const unsigned char* g, unsigned char* l) {
    __builtin_amdgcn_global_load_lds(
        (const __attribute__((address_space(1))) void*)g,
        (__attribute__((address_space(3))) void*)l,
        16, 0, 0);
}

// Unit-scale (E8M0 127 = 2^0) MX-fp8 MFMA, fmt A/B = fp8-e4m3. Verified correct R5-R17.
#define MFMA8(A, B, C) \
    __builtin_amdgcn_mfma_scale_f32_16x16x128_f8f6f4((A), (B), (C), 0, 0, 0, 127, 0, 127)

// Kernel A: L2-normalize rows, scale by sqrt(2*log2e), store fp8-e4m3 z[8192][256];
// pos[k] = 2*cos(xi_k, xj_k) in fp32. One wave per pair k. Also zero-inits out[0].
__global__ __launch_bounds__(256) void norm_kernel(const float* __restrict__ xi,
                                                   const float* __restrict__ xj,
                                                   int* __restrict__ z8,
                                                   float* __restrict__ pos,
                                                   float* __restrict__ out) {
    const int wid = threadIdx.x >> 6, lane = threadIdx.x & 63;
    const int k = blockIdx.x * 4 + wid;
    if (blockIdx.x == 0 && threadIdx.x == 0) out[0] = 0.f;
    const float4* a4 = reinterpret_cast<const float4*>(xi + (size_t)k * D);
    const float4* b4 = reinterpret_cast<const float4*>(xj + (size_t)k * D);
    float4 a = a4[lane], b = b4[lane];
    float ssi = a.x*a.x + a.y*a.y + a.z*a.z + a.w*a.w;
    float ssj = b.x*b.x + b.y*b.y + b.z*b.z + b.w*b.w;
    float dot = a.x*b.x + a.y*b.y + a.z*b.z + a.w*b.w;
#pragma unroll
    for (int off = 32; off; off >>= 1) {
        ssi += __shfl_xor(ssi, off);
        ssj += __shfl_xor(ssj, off);
        dot += __shfl_xor(dot, off);
    }
    const float inv_i = 1.0f / fmaxf(sqrtf(ssi), 1e-12f);
    const float inv_j = 1.0f / fmaxf(sqrtf(ssj), 1e-12f);
    const float si = inv_i * SCALE, sj = inv_j * SCALE;
    int pi = __builtin_amdgcn_cvt_pk_fp8_f32(a.x*si, a.y*si, 0, false);
    pi     = __builtin_amdgcn_cvt_pk_fp8_f32(a.z*si, a.w*si, pi, true);
    int pj = __builtin_amdgcn_cvt_pk_fp8_f32(b.x*sj, b.y*sj, 0, false);
    pj     = __builtin_amdgcn_cvt_pk_fp8_f32(b.z*sj, b.w*sj, pj, true);
    z8[(size_t)k * 64 + lane]        = pi;
    z8[(size_t)(k + BB) * 64 + lane] = pj;
    if (lane == 0) pos[k] = dot * inv_i * inv_j * 2.0f;
}

// Kernel B (R23): triangle + WRITE-ONCE per-wave LDS col slots.
// Post-mortems: R21's in-loop LDS atomicAdd (RMW) collapsed the software
// pipeline (VGPR 52, MfmaUtil 6.4%, 47.7us); R22's full-unroll register
// cacc[16] spilled (VGPR 64, 620 MB scratch traffic, 222us) — 16 hoisted
// iterations x 64B of ds_read results blew the 128-VGPR cap.
// R23 keeps the R19-proven unroll-4 loop and adds only: 3-add tree,
// 2 shfl_xor (quad-reduce: every lane then holds the wave's 32-row sum for
// col n*16+lrow), and ONE plain ds_write_b32 from quad==0 lanes into
// colws[wid][n*16+lrow]. Each (wave,col) slot written EXACTLY ONCE across
// the 16 iterations — no atomics, no RMW, no accumulation, distinct
// __shared__ array (no aliasing with tb => load pipeline preserved).
// End-game: tid<256 sums the 8 per-wave slots -> partial[bx][cbase+tid].
//   row-side: partial[by][bx*256 + r]   (unique writer: this block)
//   col-side: partial[bx][by*256 + c]   (unique writer: mirror never launched)
// Coverage: row r tile t: s>=t from row-side of (t,s), s<t from col-side of
// (s,t) — every partial[s][r] written exactly once; reduce_kernel unchanged.
// LDS 64+8 = 72 KB -> still 2 blocks/CU (144 < 160). fp8 layouts + swizzles
// + A-frag pin verified R5-R17; triangle indexing verified R21.
__global__ __launch_bounds__(512, 4) void sim_kernel(const unsigned char* __restrict__ z8,
                                                     float* __restrict__ partial) {
    __shared__ unsigned char tb[CPB * D];   // 64 KB tile of B columns
    __shared__ float colws[8][CPB];         // 8 KB: per-wave col sums, write-once
    const int tid = threadIdx.x;
    const int wid = tid >> 6, lane = tid & 63;
    const int lrow = lane & 15, quad = lane >> 4;

    // Decode linear block id -> upper-triangle (bx, by), by >= bx.
    int t = blockIdx.x, bx = 0;
    while (t >= (NSPLIT - bx)) { t -= (NSPLIT - bx); ++bx; }
    const int by = bx + t;

    const int r0 = bx * 256 + wid * 32;     // this wave's 32 rows (row tile bx)
    const int cbase = by * CPB;             // this block's 256 cols (col tile by)

    // Staging: 8 rounds x 8 KB (512 thr x 16 B). Round i, thread tid writes
    // physical granule-linear i*512 + tid -> row r = i*32 + (tid>>4), physical
    // granule p = tid&15. Source logical granule = p ^ (r&15) = (tid&15)^((tid>>4)&15).
    {
        const int srcg = (tid & 15) ^ ((tid >> 4) & 15);
        const unsigned char* gs = z8 + (size_t)(cbase + (tid >> 4)) * D + srcg * 16;
        unsigned char* ds = tb + tid * 16;
#pragma unroll
        for (int i = 0; i < 8; ++i)
            async16(gs + (size_t)i * 32 * D, ds + i * 8192);
    }

    // A fragments: 32 rows x K=256. Layout (16x16x128 f8f6f4): row = lane&15,
    // k-bytes = (lane>>4)*32 + linear; k-half 1 at +128. Pinned vs remat (R9/R10).
    const unsigned char* abase = z8 + (size_t)(r0 + lrow) * D + quad * 32;
    i32x8 a0k0 = *reinterpret_cast<const i32x8*>(abase             );
    i32x8 a0k1 = *reinterpret_cast<const i32x8*>(abase        + 128);
    i32x8 a1k0 = *reinterpret_cast<const i32x8*>(abase + 16*D      );
    i32x8 a1k1 = *reinterpret_cast<const i32x8*>(abase + 16*D + 128);
    asm volatile("" : "+v"(a0k0), "+v"(a0k1), "+v"(a1k0), "+v"(a1k1));

    f32x4 racc0 = {0.f,0.f,0.f,0.f}, racc1 = {0.f,0.f,0.f,0.f};

    __syncthreads();   // staging DMA drained, 64 KB tile complete

    // Loop: per group, 4 ds_read_b128 + 4 MFMA + 8 exp2 + col tree/shfl/write.
    // Read swizzle (verified): col row = n*16+lrow, physical granule = logical ^ lrow;
    // b128 pairs (pe, pe^1) reassemble the 32-B operand halves.
    const int pe0 = (quad * 2) ^ lrow;        // k-half 0 even granule
    const int pe1 = (8 + quad * 2) ^ lrow;    // k-half 1 even granule
    const unsigned char* rbp = tb + lrow * D;
#pragma unroll 4
    for (int n = 0; n < NG; ++n) {
        const i32x4 lo0 = *reinterpret_cast<const i32x4*>(rbp + pe0*16);
        const i32x4 hi0 = *reinterpret_cast<const i32x4*>(rbp + (pe0^1)*16);
        const i32x4 lo1 = *reinterpret_cast<const i32x4*>(rbp + pe1*16);
        const i32x4 hi1 = *reinterpret_cast<const i32x4*>(rbp + (pe1^1)*16);
        rbp += 16 * D;
        const i32x8 b0 = __builtin_shufflevector(lo0, hi0, 0,1,2,3,4,5,6,7);
        const i32x8 b1 = __builtin_shufflevector(lo1, hi1, 0,1,2,3,4,5,6,7);

        f32x4 c0 = {0.f,0.f,0.f,0.f}, c1 = {0.f,0.f,0.f,0.f};
        c0 = MFMA8(a0k0, b0, c0);  c0 = MFMA8(a0k1, b1, c0);
        c1 = MFMA8(a1k0, b0, c1);  c1 = MFMA8(a1k1, b1, c1);

        const float e0 = __builtin_amdgcn_exp2f(c0[0]);
        const float e1 = __builtin_amdgcn_exp2f(c0[1]);
        const float e2 = __builtin_amdgcn_exp2f(c0[2]);
        const float e3 = __builtin_amdgcn_exp2f(c0[3]);
        const float e4 = __builtin_amdgcn_exp2f(c1[0]);
        const float e5 = __builtin_amdgcn_exp2f(c1[1]);
        const float e6 = __builtin_amdgcn_exp2f(c1[2]);
        const float e7 = __builtin_amdgcn_exp2f(c1[3]);
        racc0[0] += e0;  racc0[1] += e1;  racc0[2] += e2;  racc0[3] += e3;
        racc1[0] += e4;  racc1[1] += e5;  racc1[2] += e6;  racc1[3] += e7;

        // Col-side: lane's 8 rows -> quad-reduce (bits 4,5) -> wave's 32-row
        // sum for col n*16+lrow; quad==0 lanes store (write-once, non-atomic,
        // 16 distinct banks).
        float cs = ((e0 + e1) + (e2 + e3)) + ((e4 + e5) + (e6 + e7));
        cs += __shfl_xor(cs, 16);
        cs += __shfl_xor(cs, 32);
        if (quad == 0) colws[wid][n * 16 + lrow] = cs;
    }

    // Row sums: reduce over lane bits 0-3 (the col index); row = quad*4 + j.
#define REDUCE_STORE(RV, M)                                                     \
    {                                                                           \
        _Pragma("unroll")                                                       \
        for (int j = 0; j < 4; ++j) {                                           \
            float v = (RV)[j];                                                  \
            v += __shfl_xor(v, 1);                                              \
            v += __shfl_xor(v, 2);                                              \
            v += __shfl_xor(v, 4);                                              \
            v += __shfl_xor(v, 8);                                              \
            if (lrow == 0)                                                      \
                partial[(size_t)by * R2 + r0 + (M)*16 + quad*4 + j] = v;        \
        }                                                                       \
    }
    REDUCE_STORE(racc0, 0)
    REDUCE_STORE(racc1, 1)
#undef REDUCE_STORE

    // Col-side end-game: sum the 8 per-wave slots (off-diagonal blocks only;
    // diagonal's mirror is itself — row-side already covers it).
    __syncthreads();   // all waves' colws writes visible
    if (bx != by && tid < CPB) {
        float s = 0.f;
#pragma unroll
        for (int w = 0; w < 8; ++w) s += colws[w][tid];
        partial[(size_t)bx * R2 + cbase + tid] = s;
    }
}

// Kernel C: loss_r = log(exp(p_r) + S_r - e^2) - p_r ; atomicAdd(out, blocksum/R2).
// 32 blocks x 256 threads (256 rows each); out zero-initialized by norm_kernel.
__global__ __launch_bounds__(256) void reduce_kernel(const float* __restrict__ partial,
                                                     const float* __restrict__ pos,
                                                     float* __restrict__ out) {
    __shared__ float wsum[4];
    const int tid = threadIdx.x;
    const int r = blockIdx.x * 256 + tid;
    float S = 0.f;
#pragma unroll
    for (int s = 0; s < NSPLIT; ++s) S += partial[(size_t)s * R2 + r];
    const float p = pos[r & (BB - 1)];
    float lsum = __logf(__expf(p) + S - E2) - p;
#pragma unroll
    for (int off = 32; off; off >>= 1) lsum += __shfl_xor(lsum, off);
    if ((tid & 63) == 0) wsum[tid >> 6] = lsum;
    __syncthreads();
    if (tid == 0) {
        float t = wsum[0] + wsum[1] + wsum[2] + wsum[3];
        atomicAdd(out, t * (1.0f / (float)R2));
    }
}

extern "C" void kernel_launch(void* const* d_in, const int* in_sizes, int n_in,
                              void* d_out, int out_size, void* d_ws, size_t ws_size,
                              hipStream_t stream) {
    (void)in_sizes; (void)n_in; (void)out_size; (void)ws_size;
    const float* xi = (const float*)d_in[0];
    const float* xj = (const float*)d_in[1];
    float* out = (float*)d_out;

    unsigned char* z8 = (unsigned char*)d_ws;                                  // 8192*256 = 2 MB
    float* partial = (float*)((char*)d_ws + (size_t)R2 * D);                   // 32*8192*4 = 1 MB
    float* pos     = (float*)((char*)d_ws + (size_t)R2 * D + (size_t)NSPLIT*R2*4);  // 16 KB

    norm_kernel<<<BB / 4, 256, 0, stream>>>(xi, xj, (int*)z8, pos, out);
    sim_kernel<<<NTRI, 512, 0, stream>>>(z8, partial);
    reduce_kernel<<<R2 / 256, 256, 0, stream>>>(partial, pos, out);
}